// Round 15
// baseline (19.320 us; speedup 1.0000x reference)
//
#include <hip/hip_runtime.h>
#include <math.h>

#define NTH 256

typedef float f2 __attribute__((ext_vector_type(2)));

__device__ __forceinline__ float frcp(float x) { return __builtin_amdgcn_rcpf(x); }
// reciprocal with sign-preserving epsilon (ref's +EPS role); frcp_eps(-d) == -frcp_eps(d)
__device__ __forceinline__ float frcp_eps(float d) {
    float es = __int_as_float((__float_as_int(d) & 0x80000000) | 0x322BCC77); // copysign(1e-8f,d)
    return __builtin_amdgcn_rcpf(d + es);
}

__device__ __forceinline__ f2 fmin2(f2 a, f2 b) { return __builtin_elementwise_min(a, b); }
__device__ __forceinline__ f2 fmax2(f2 a, f2 b) { return __builtin_elementwise_max(a, b); }
__device__ __forceinline__ f2 fma2(f2 a, f2 b, f2 c) { return __builtin_elementwise_fma(a, b, c); }
__device__ __forceinline__ f2 fabs2(f2 a) { return __builtin_elementwise_abs(a); }
__device__ __forceinline__ f2 rcpe2(f2 d) { f2 r; r.x = frcp_eps(d.x); r.y = frcp_eps(d.y); return r; }
__device__ __forceinline__ f2 rcp2e8(f2 d) {  // 1/(d+1e-8)
    f2 r; r.x = frcp(d.x + 1e-8f); r.y = frcp(d.y + 1e-8f); return r;
}

// 4-byte-aligned overlapping 16B loads (boxes at 28B stride)
typedef float float4a __attribute__((ext_vector_type(4), aligned(4)));
__device__ __forceinline__ void load_box(const float* __restrict__ p,
                                         float& cx, float& cy,
                                         float& lw, float& ll, float& yaw) {
    float4a a = *reinterpret_cast<const float4a*>(p);      // fields 0,1,2,3
    float4a b = *reinterpret_cast<const float4a*>(p + 3);  // fields 3,4,5,6
    cx = a.x; cy = a.y; lw = a.w; ll = b.y; yaw = b.w;
}

// Green's-theorem closed-form box-clip area (R9/R10), now PACKED-FP32:
// two box pairs per f2 chain (components = independent pairs); mul/add/fma
// lower to v_pk_*_f32 (gfx950 packed math), min/max/selects/trans stay scalar.
__device__ __forceinline__ f2 giou_loss2(const float* __restrict__ box,
                                         const float* __restrict__ tbox,
                                         int ca, int cb)
{
    float ax0, ay0, alw0, all0, ayaw0, ax1, ay1, alw1, all1, ayaw1;
    float bx0, by0, blw0, bll0, byaw0, bx1, by1, blw1, bll1, byaw1;
    load_box(box  + (size_t)ca * 7, ax0, ay0, alw0, all0, ayaw0);
    load_box(box  + (size_t)cb * 7, ax1, ay1, alw1, all1, ayaw1);
    load_box(tbox + (size_t)ca * 7, bx0, by0, blw0, bll0, byaw0);
    load_box(tbox + (size_t)cb * 7, bx1, by1, blw1, bll1, byaw1);

    f2 cx1 = {ax0, ax1}, cy1 = {ay0, ay1};
    f2 cx2 = {bx0, bx1}, cy2 = {by0, by1};
    f2 w1, l1, w2, l2, s1, c1, s2, c2;
    w1.x = __expf(alw0); w1.y = __expf(alw1);
    l1.x = __expf(all0); l1.y = __expf(all1);
    w2.x = __expf(blw0); w2.y = __expf(blw1);
    l2.x = __expf(bll0); l2.y = __expf(bll1);
    s1.x = __sinf(ayaw0); s1.y = __sinf(ayaw1);
    c1.x = __cosf(ayaw0); c1.y = __cosf(ayaw1);
    s2.x = __sinf(byaw0); s2.y = __sinf(byaw1);
    c2.x = __cosf(byaw0); c2.y = __cosf(byaw1);

    f2 hx1 = 0.5f * w1, hy1 = 0.5f * l1;
    f2 hx  = 0.5f * w2, hy  = 0.5f * l2;    // clip-box half-extents

    // world-frame enclosing bbox via exact extent identity |u|+|v|
    f2 e1x = fma2(hx1, fabs2(c1), hy1 * fabs2(s1));
    f2 e1y = fma2(hx1, fabs2(s1), hy1 * fabs2(c1));
    f2 e2x = fma2(hx, fabs2(c2), hy * fabs2(s2));
    f2 e2y = fma2(hx, fabs2(s2), hy * fabs2(c2));
    f2 enc;
    {
        f2 xmin = fmin2(cx1 - e1x, cx2 - e2x);
        f2 xmax = fmax2(cx1 + e1x, cx2 + e2x);
        f2 ymin = fmin2(cy1 - e1y, cy2 - e2y);
        f2 ymax = fmax2(cy1 + e1y, cy2 + e2y);
        enc = (xmax - xmin) * (ymax - ymin);
    }

    // transform quad1 into box2's frame
    f2 sr = s1 * c2 - c1 * s2;
    f2 cr = c1 * c2 + s1 * s2;
    f2 tx = cx1 - cx2, ty = cy1 - cy2;
    f2 dxc =  c2 * tx + s2 * ty;
    f2 dyc = -s2 * tx + c2 * ty;
    f2 ux = hx1 * cr, uy = hx1 * sr;
    f2 vx = -hy1 * sr, vy = hy1 * cr;

    f2 qx[4], qy[4];
    qx[0] = dxc - ux - vx;  qy[0] = dyc - uy - vy;
    qx[1] = dxc + ux - vx;  qy[1] = dyc + uy - vy;
    qx[2] = dxc + ux + vx;  qy[2] = dyc + uy + vy;
    qx[3] = dxc - ux + vx;  qy[3] = dyc - uy + vy;

    // edge vectors: e0=+2u e1=+2v e2=-2u e3=-2v; 4 shared eps-rcps per comp
    f2 Ux = 2.0f * ux, Uy = 2.0f * uy;
    f2 Vx = 2.0f * vx, Vy = 2.0f * vy;
    f2 rUx = rcpe2(Ux), rUy = rcpe2(Uy);
    f2 rVx = rcpe2(Vx), rVy = rcpe2(Vy);

    // hoisted per-vertex threshold compares (per component)
    bool gTa[4], gTb[4], gBa[4], gBb[4];
#pragma unroll
    for (int k = 0; k < 4; ++k) {
        gTa[k] = qy[k].x > hy.x;  gTb[k] = qy[k].y > hy.y;
        gBa[k] = qy[k].x > -hy.x; gBb[k] = qy[k].y > -hy.y;
    }

    const float INFP = __int_as_float(0x7f800000);
    const f2 ZERO = {0.0f, 0.0f};
    const f2 ONE  = {1.0f, 1.0f};
    f2 areaP = ZERO;
    f2 xTmin = {INFP, INFP}, xTmax = {-INFP, -INFP};
    f2 xBmin = {INFP, INFP}, xBmax = {-INFP, -INFP};
#pragma unroll
    for (int i = 0; i < 4; ++i) {
        f2 px = qx[i], py = qy[i];
        int ip1 = (i + 1) & 3;
        f2 dxe = (i == 0) ? Ux : (i == 1) ? Vx : (i == 2) ? -Ux : -Vx;
        f2 dye = (i == 0) ? Uy : (i == 1) ? Vy : (i == 2) ? -Uy : -Vy;
        f2 rdx = (i == 0) ? rUx : (i == 1) ? rVx : (i == 2) ? -rUx : -rVx;
        f2 rdy = (i == 0) ? rUy : (i == 1) ? rVy : (i == 2) ? -rUy : -rVy;

        // in-box parameter interval (packed clamp arithmetic)
        f2 ta = (-hx - px) * rdx, tb = (hx - px) * rdx;
        f2 txlo = fmin2(ta, tb), txhi = fmax2(ta, tb);
        f2 tc = (-hy - py) * rdy, td = (hy - py) * rdy;
        f2 tylo = fmin2(tc, td), tyhi = fmax2(tc, td);
        f2 t0 = fmax2(fmax2(txlo, tylo), ZERO);
        f2 t1 = fmin2(fmin2(txhi, tyhi), ONE);
        f2 dt = fmax2(t1 - t0, ZERO);
        areaP -= dxe * dt * fma2(0.5f * dye, t0 + t1, py);   // -∫ y dx

        // crossings with horizontal box lines (correction terms)
        f2 xT = fma2(td, dxe, px);
        f2 xB = fma2(tc, dxe, px);
        bool crTa = gTa[i] != gTa[ip1], crTb = gTb[i] != gTb[ip1];
        bool crBa = gBa[i] != gBa[ip1], crBb = gBb[i] != gBb[ip1];
        f2 sTmin = {crTa ? xT.x : INFP,  crTb ? xT.y : INFP};
        f2 sTmax = {crTa ? xT.x : -INFP, crTb ? xT.y : -INFP};
        f2 sBmin = {crBa ? xB.x : INFP,  crBb ? xB.y : INFP};
        f2 sBmax = {crBa ? xB.x : -INFP, crBb ? xB.y : -INFP};
        xTmin = fmin2(xTmin, sTmin);  xTmax = fmax2(xTmax, sTmax);
        xBmin = fmin2(xBmin, sBmin);  xBmax = fmax2(xBmax, sBmax);
    }
    // empty-crossing: -INF-INF=-INF -> max(0,.)=0, no guards
    f2 Ltop = fmax2(ZERO, fmin2(xTmax, hx) - fmax2(xTmin, -hx));
    f2 Lbot = fmax2(ZERO, fmin2(xBmax, hx) - fmax2(xBmin, -hx));
    f2 inter = fabs2(fma2(hy, Ltop + Lbot, areaP));

    f2 area1 = w1 * l1, area2 = w2 * l2;
    f2 uni = area1 + area2 - inter;
    f2 giou = inter * rcp2e8(uni) - (enc - uni) * rcp2e8(enc);
    return 1.0f - giou;
}

__global__ __launch_bounds__(NTH) void giou_kernel(
    const float* __restrict__ box, const float* __restrict__ tbox,
    double* __restrict__ wsum, int N)
{
    __shared__ double red[4];
    const int tid = threadIdx.x;
    const int base = blockIdx.x * (4 * NTH) + tid;
    const int g0 = base, g1 = base + NTH, g2 = base + 2 * NTH, g3 = base + 3 * NTH;

    // branchless tail: clamp index, select-to-zero
    int c0 = g0 < N ? g0 : N - 1;
    int c1 = g1 < N ? g1 : N - 1;
    int c2 = g2 < N ? g2 : N - 1;
    int c3 = g3 < N ? g3 : N - 1;
    f2 lA = giou_loss2(box, tbox, c0, c1);
    f2 lB = giou_loss2(box, tbox, c2, c3);
    float loss = (g0 < N ? lA.x : 0.0f) + (g1 < N ? lA.y : 0.0f)
               + (g2 < N ? lB.x : 0.0f) + (g3 < N ? lB.y : 0.0f);

    // reduction: f32 wave shuffle -> f64 block partial -> per-block store
#pragma unroll
    for (int o = 32; o > 0; o >>= 1) loss += __shfl_down(loss, o, 64);

    if ((tid & 63) == 0) red[tid >> 6] = (double)loss;
    __syncthreads();
    if (tid == 0)
        wsum[blockIdx.x] = red[0] + red[1] + red[2] + red[3];  // no memset, no atomic
}

__global__ __launch_bounds__(NTH) void finalize_kernel(
    const double* __restrict__ ws, int nblk,
    const int* __restrict__ avgp, float* __restrict__ out)
{
    __shared__ double r[NTH];
    int t = threadIdx.x;
    double v = 0.0;
    for (int i = t; i < nblk; i += NTH) v += ws[i];
    r[t] = v;
    __syncthreads();
#pragma unroll
    for (int s = NTH / 2; s > 0; s >>= 1) {
        if (t < s) r[t] += r[t + s];
        __syncthreads();
    }
    if (t == 0) {
        int ib = *avgp;
        float fb = __int_as_float(ib);
        float av;
        if (ib > 0 && fabsf(fb) < 1e-20f) av = (float)ib;   // int32 payload
        else av = fb;                                        // f32 payload fallback
        if (!(av >= 1.0f)) av = 1.0f;
        out[0] = (float)(r[0] / (double)av);
    }
}

extern "C" void kernel_launch(void* const* d_in, const int* in_sizes, int n_in,
                              void* d_out, int out_size, void* d_ws, size_t ws_size,
                              hipStream_t stream) {
    const float* box  = (const float*)d_in[0];
    const float* tbox = (const float*)d_in[1];
    const int*   avgp = (const int*)d_in[2];
    int N = in_sizes[0] / 7;
    double* ws = (double*)d_ws;

    int blocks = (N + 4 * NTH - 1) / (4 * NTH);
    giou_kernel<<<blocks, NTH, 0, stream>>>(box, tbox, ws, N);
    finalize_kernel<<<1, NTH, 0, stream>>>(ws, blocks, avgp, (float*)d_out);
}